// Round 5
// baseline (148.375 us; speedup 1.0000x reference)
//
#include <hip/hip_runtime.h>

#define HH 50
#define WW 50
#define EPSF 1e-8f

// Histogram: x (birth) in [0,1] -> 160 bins; y (pers) in [-0.5, 1.0] -> 240 bins.
// Nearest-bin splat (1 LDS atomic/point). p < -0.5 dropped: gy <= exp(-12.5).
#define BXH 160
#define BYH 240
#define Y0F (-0.5f)
#define YSPAN 1.5f
#define REPSZ (BXH * BYH)            // 38400 bins; LDS 150 KB; bf16 replica 76.8 KB

// ws float offsets
#define GXOFF 0                       // gx_tab[w][ix] : 50*160 = 8000
#define GYOFF (GXOFF + WW * BXH)      // gy_tab[h][iy] : 50*240 = 12000
#define POFF  (GYOFF + HH * BYH)      // P[iy][w]      : 240*50 = 12000
#define IMGOFF (POFF + BYH * WW)      // img           : 2500
#define CNTOFF (IMGOFF + HH * WW + 12) // two int tickets (padded)
#define REPOFF (CNTOFF + 4)           // 16B-aligned; bf16 replicas follow

__device__ __forceinline__ unsigned bf16pk(float a, float b) {
    unsigned ua = __float_as_uint(a), ub = __float_as_uint(b);
    ua = (ua + 0x7FFFu + ((ua >> 16) & 1u)) >> 16;       // RNE
    ub = (ub + 0x7FFFu + ((ub >> 16) & 1u)) >> 16;
    return ua | (ub << 16);
}

__device__ __forceinline__ void splat1(float b, float death, float* hist) {
    const float p = death - b;               // pers == weight (may be negative)
    if (p < Y0F) return;
    int ix = (int)(b * (float)BXH);          // b >= 0: trunc == floor
    int iy = (int)((p - Y0F) * ((float)BYH / YSPAN));
    ix = min(ix, BXH - 1);
    iy = min(iy, BYH - 1);
    atomicAdd(&hist[iy * BXH + ix], p);
}

// ---------------------------------------------------------------------------
// K1: per-block private LDS histogram (nearest splat), dump replica as bf16.
// Block 0 additionally builds the exp lookup tables + zeroes the tickets.
// ---------------------------------------------------------------------------
__global__ __launch_bounds__(1024) void pie_hist_lds(
    const float4* __restrict__ pairs4, int n,
    const float* __restrict__ grid_x, const float* __restrict__ grid_y,
    const float* __restrict__ sigma_p, float* __restrict__ ws, int R)
{
    __shared__ float hist[REPSZ];            // 150 KB -> 1 block/CU
    const int t = threadIdx.x;

    {   // vectorized LDS zero (ds_write_b128)
        const float4 z = make_float4(0.f, 0.f, 0.f, 0.f);
        float4* h4 = (float4*)hist;
        #pragma unroll
        for (int i = t; i < REPSZ / 4; i += 1024) h4[i] = z;
    }

    if (blockIdx.x == 0) {
        if (t == 0) { ((int*)ws)[CNTOFF] = 0; ((int*)ws)[CNTOFF + 1] = 0; }
        const float s = *sigma_p;
        const float a = 1.0f / (2.0f * s * s);
        for (int i = t; i < WW * BXH; i += 1024) {
            const int w = i / BXH, ix = i - w * BXH;
            const float c = (ix + 0.5f) * (1.0f / BXH);
            const float d = grid_x[w] - c;
            ws[GXOFF + i] = __expf(-d * d * a);
        }
        for (int i = t; i < HH * BYH; i += 1024) {
            const int h = i / BYH, iy = i - h * BYH;
            const float c = Y0F + (iy + 0.5f) * (YSPAN / (float)BYH);
            const float d = grid_y[h] - c;
            ws[GYOFF + i] = __expf(-d * d * a);
        }
    }
    __syncthreads();

    const int n2 = n >> 1;                   // two points per float4
    const int stride = R * 1024;
    #pragma unroll 2
    for (int i = blockIdx.x * 1024 + t; i < n2; i += stride) {
        const float4 q = pairs4[i];
        splat1(q.x, q.y, hist);
        splat1(q.z, q.w, hist);
    }
    if ((n & 1) && blockIdx.x == 0 && t == 0) {
        const float2 last = ((const float2*)pairs4)[n - 1];
        splat1(last.x, last.y, hist);
    }
    __syncthreads();

    // dump as bf16: 2x ds_read_b128 -> 1x global_store_dwordx4 (8 bins/iter)
    uint4* dst = (uint4*)((char*)ws + (size_t)REPOFF * 4 + (size_t)blockIdx.x * (REPSZ * 2));
    const float4* src = (const float4*)hist;
    #pragma unroll
    for (int i = t; i < REPSZ / 8; i += 1024) {
        const float4 a = src[2 * i], b = src[2 * i + 1];
        uint4 o;
        o.x = bf16pk(a.x, a.y); o.y = bf16pk(a.z, a.w);
        o.z = bf16pk(b.x, b.y); o.w = bf16pk(b.z, b.w);
        dst[i] = o;
    }
}

// ---------------------------------------------------------------------------
// K2 (fused c1+c2): 240 blocks, 640 threads.
// Phase A (all blocks): merge R bf16 replicas for row `rowi`, contract vs gx:
//   P[rowi][w] = sum_ix row[ix] * gx_tab[w][ix];  ticket1.
// Blocks >= 50 exit. Blocks < 50 spin until all 240 P rows visible (all blocks
// co-resident: grid 240 <= 256 CUs, 43 KB LDS), then
// Phase B: img[h][w] = sum_r gy[h][r] * P[r][w];  ticket2; last block does
// max + normalize + store to out.
// ---------------------------------------------------------------------------
__global__ __launch_bounds__(640) void pie_c12(float* __restrict__ ws,
                                               float* __restrict__ out, int R)
{
    __shared__ float part[16 * BXH];         // 10 KB (reused in phase B)
    __shared__ float row[BXH];
    __shared__ float gxl[WW * (BXH + 1)];    // stride 161: conflict-free dot
    __shared__ float redmax[10];
    __shared__ int flag;
    const int t = threadIdx.x;
    const int rowi = blockIdx.x;
    int* cnt1 = (int*)ws + CNTOFF;
    int* cnt2 = cnt1 + 1;

    for (int i = t; i < WW * BXH; i += 640) {
        const int w = i / BXH, ix = i - w * BXH;
        gxl[w * (BXH + 1) + ix] = ws[GXOFF + i];
    }

    // ---- Phase A: merge + x-contraction ----
    {
        const int g = t / 40;                // replica group 0..15
        const int s = t - g * 40;            // uint2 slot within row (4 bins)
        const char* repbase = (const char*)ws + (size_t)REPOFF * 4;
        float a0 = 0.f, a1 = 0.f, a2 = 0.f, a3 = 0.f;
        #pragma unroll 4
        for (int r = g; r < R; r += 16) {
            const uint2 u = *(const uint2*)(repbase + (size_t)r * (REPSZ * 2)
                                            + (size_t)(rowi * 40 + s) * 8);
            a0 += __uint_as_float(u.x << 16);
            a1 += __uint_as_float(u.x & 0xFFFF0000u);
            a2 += __uint_as_float(u.y << 16);
            a3 += __uint_as_float(u.y & 0xFFFF0000u);
        }
        ((float4*)part)[g * 40 + s] = make_float4(a0, a1, a2, a3);
    }
    __syncthreads();

    if (t < BXH) {
        float sum = 0.0f;
        #pragma unroll
        for (int k = 0; k < 16; ++k) sum += part[k * BXH + t];
        row[t] = sum;
    }
    __syncthreads();

    if (t < WW) {
        float acc = 0.0f;
        #pragma unroll 4
        for (int k = 0; k < BXH; ++k)
            acc += row[k] * gxl[t * (BXH + 1) + k];
        ws[POFF + rowi * WW + t] = acc;
    }
    __threadfence();                         // release P row (every thread)
    __syncthreads();
    if (t == 0) atomicAdd(cnt1, 1);

    if (rowi >= HH) return;                  // rows 50..239: done

    // ---- spin until all 240 P rows are published ----
    if (t == 0) {
        while (atomicAdd(cnt1, 0) < BYH) __builtin_amdgcn_s_sleep(1);
        flag = 1;
    }
    __syncthreads();
    __threadfence();                         // acquire P

    // ---- Phase B: y-contraction for row h = rowi ----
    if (t < 600) {                           // 12 chunks x 50 w
        const int w = t % WW;
        const int c = t / WW;                // 0..11, 20 rows each
        const float* gy = ws + GYOFF + rowi * BYH;
        const float* P  = ws + POFF;
        const int r0 = c * 20;
        float acc = 0.0f;
        #pragma unroll 4
        for (int r = r0; r < r0 + 20; ++r)
            acc += gy[r] * P[r * WW + w];
        part[t] = acc;
    }
    __syncthreads();
    if (t < WW) {
        float s = 0.0f;
        #pragma unroll
        for (int k = 0; k < 12; ++k) s += part[k * WW + t];
        ws[IMGOFF + rowi * WW + t] = s;
    }
    __threadfence();                         // release img row
    __syncthreads();
    if (t == 0) {
        const int old = atomicAdd(cnt2, 1);
        flag = (old == HH - 1);
    }
    __syncthreads();
    if (!flag) return;
    __threadfence();                         // acquire all img rows

    // ---- last block: max + normalize ----
    float m = -1e30f;
    for (int i = t; i < HH * WW; i += 640) m = fmaxf(m, ws[IMGOFF + i]);
    #pragma unroll
    for (int off = 32; off > 0; off >>= 1)
        m = fmaxf(m, __shfl_down(m, off));
    const int wv = t >> 6, ln = t & 63;
    if (ln == 0) redmax[wv] = m;
    __syncthreads();
    if (t == 0) {
        float mm = redmax[0];
        #pragma unroll
        for (int k = 1; k < 10; ++k) mm = fmaxf(mm, redmax[k]);
        redmax[0] = mm;
    }
    __syncthreads();

    const float inv = 1.0f / (redmax[0] + EPSF);
    for (int i = t; i < HH * WW; i += 640) out[i] = ws[IMGOFF + i] * inv;
}

// ---------------------------------------------------------------------------
extern "C" void kernel_launch(void* const* d_in, const int* in_sizes, int n_in,
                              void* d_out, int out_size, void* d_ws, size_t ws_size,
                              hipStream_t stream) {
    const float4* pairs4 = (const float4*)d_in[0];
    const float*  sigma  = (const float*)d_in[1];
    const float*  grid_x = (const float*)d_in[2];
    const float*  grid_y = (const float*)d_in[3];
    float* ws  = (float*)d_ws;
    float* out = (float*)d_out;
    const int n = in_sizes[0] / 2;

    // replica count from available workspace (bf16 replicas: 76.8 KB each)
    const long avail_bytes = (long)ws_size - (long)REPOFF * 4;
    long cap = avail_bytes / (REPSZ * 2);
    int R = (int)(cap < 256 ? cap : 256);
    if (R < 1) R = 1;

    pie_hist_lds<<<R, 1024, 0, stream>>>(pairs4, n, grid_x, grid_y, sigma, ws, R);
    pie_c12<<<BYH, 640, 0, stream>>>(ws, out, R);
}

// Round 6
// 105.351 us; speedup vs baseline: 1.4084x; 1.4084x over previous
//
#include <hip/hip_runtime.h>

#define HH 50
#define WW 50
#define EPSF 1e-8f

// Histogram: x (birth) in [0,1] -> 160 bins; y (pers) in [-0.5, 1.0] -> 240 bins.
// Nearest-bin splat (1 LDS atomic/point). p < -0.5 dropped: gy <= exp(-12.5).
#define BXH 160
#define BYH 240
#define Y0F (-0.5f)
#define YSPAN 1.5f
#define REPSZ (BXH * BYH)            // 38400 bins; LDS 150 KB; bf16 replica 76.8 KB

// ws float offsets
#define GXOFF 0                       // gx_tab[w][ix] : 50*160 = 8000
#define GYOFF (GXOFF + WW * BXH)      // gy_tab[h][iy] : 50*240 = 12000
#define POFF  (GYOFF + HH * BYH)      // P[iy][w]      : 240*50 = 12000
#define IMGOFF (POFF + BYH * WW)      // img           : 2500
#define CNTOFF (IMGOFF + HH * WW + 12) // int ticket counter (padded)
#define REPOFF (CNTOFF + 4)           // 16B-aligned; bf16 replicas follow

__device__ __forceinline__ unsigned bf16pk(float a, float b) {
    unsigned ua = __float_as_uint(a), ub = __float_as_uint(b);
    ua = (ua + 0x7FFFu + ((ua >> 16) & 1u)) >> 16;       // RNE
    ub = (ub + 0x7FFFu + ((ub >> 16) & 1u)) >> 16;
    return ua | (ub << 16);
}

__device__ __forceinline__ void splat1(float b, float death, float* hist) {
    const float p = death - b;               // pers == weight (may be negative)
    if (p < Y0F) return;
    int ix = (int)(b * (float)BXH);          // b >= 0: trunc == floor
    int iy = (int)((p - Y0F) * ((float)BYH / YSPAN));
    ix = min(ix, BXH - 1);
    iy = min(iy, BYH - 1);
    atomicAdd(&hist[iy * BXH + ix], p);
}

// ---------------------------------------------------------------------------
// K1: per-block private LDS histogram (nearest splat), dump replica as bf16.
// Block 0 additionally builds the exp lookup tables + zeroes the K3 ticket.
// NOTE (R5 lesson): do NOT fuse c1/c2 behind an intra-kernel spin barrier —
// 50 blocks polling one atomic line starved the 240 ticket increments (69 us).
// ---------------------------------------------------------------------------
__global__ __launch_bounds__(1024) void pie_hist_lds(
    const float4* __restrict__ pairs4, int n,
    const float* __restrict__ grid_x, const float* __restrict__ grid_y,
    const float* __restrict__ sigma_p, float* __restrict__ ws, int R)
{
    __shared__ float hist[REPSZ];            // 150 KB -> 1 block/CU
    const int t = threadIdx.x;

    {   // vectorized LDS zero (ds_write_b128)
        const float4 z = make_float4(0.f, 0.f, 0.f, 0.f);
        float4* h4 = (float4*)hist;
        #pragma unroll
        for (int i = t; i < REPSZ / 4; i += 1024) h4[i] = z;
    }

    if (blockIdx.x == 0) {
        if (t == 0) ((int*)ws)[CNTOFF] = 0;  // K3 ticket
        const float s = *sigma_p;
        const float a = 1.0f / (2.0f * s * s);
        for (int i = t; i < WW * BXH; i += 1024) {
            const int w = i / BXH, ix = i - w * BXH;
            const float c = (ix + 0.5f) * (1.0f / BXH);
            const float d = grid_x[w] - c;
            ws[GXOFF + i] = __expf(-d * d * a);
        }
        for (int i = t; i < HH * BYH; i += 1024) {
            const int h = i / BYH, iy = i - h * BYH;
            const float c = Y0F + (iy + 0.5f) * (YSPAN / (float)BYH);
            const float d = grid_y[h] - c;
            ws[GYOFF + i] = __expf(-d * d * a);
        }
    }
    __syncthreads();

    const int n2 = n >> 1;                   // two points per float4
    const int stride = R * 1024;
    #pragma unroll 4
    for (int i = blockIdx.x * 1024 + t; i < n2; i += stride) {
        const float4 q = pairs4[i];
        splat1(q.x, q.y, hist);
        splat1(q.z, q.w, hist);
    }
    if ((n & 1) && blockIdx.x == 0 && t == 0) {
        const float2 last = ((const float2*)pairs4)[n - 1];
        splat1(last.x, last.y, hist);
    }
    __syncthreads();

    // dump as bf16: 2x ds_read_b128 -> 1x global_store_dwordx4 (8 bins/iter)
    uint4* dst = (uint4*)((char*)ws + (size_t)REPOFF * 4 + (size_t)blockIdx.x * (REPSZ * 2));
    const float4* src = (const float4*)hist;
    #pragma unroll
    for (int i = t; i < REPSZ / 8; i += 1024) {
        const float4 a = src[2 * i], b = src[2 * i + 1];
        uint4 o;
        o.x = bf16pk(a.x, a.y); o.y = bf16pk(a.z, a.w);
        o.z = bf16pk(b.x, b.y); o.w = bf16pk(b.z, b.w);
        dst[i] = o;
    }
}

// ---------------------------------------------------------------------------
// K2: one block per y-row. Merge R bf16 replicas for this row (uint2 = 4 bins
// per load), then P[row][w] = sum_ix row[ix] * gx_tab[w][ix].
// 640 threads: 16 replica-groups x 40 uint2 slots.
// ---------------------------------------------------------------------------
__global__ __launch_bounds__(640) void pie_c1(float* __restrict__ ws, int R)
{
    __shared__ float part[16 * BXH];         // 10 KB
    __shared__ float row[BXH];
    __shared__ float gxl[WW * (BXH + 1)];    // stride 161: conflict-free dot
    const int t = threadIdx.x;
    const int rowi = blockIdx.x;

    for (int i = t; i < WW * BXH; i += 640) {
        const int w = i / BXH, ix = i - w * BXH;
        gxl[w * (BXH + 1) + ix] = ws[GXOFF + i];
    }

    const int g = t / 40;                    // replica group 0..15
    const int s = t - g * 40;                // uint2 slot within row (4 bins)
    {
        const char* repbase = (const char*)ws + (size_t)REPOFF * 4;
        float a0 = 0.0f, a1 = 0.0f, a2 = 0.0f, a3 = 0.0f;
        #pragma unroll 4
        for (int r = g; r < R; r += 16) {
            const uint2 u = *(const uint2*)(repbase + (size_t)r * (REPSZ * 2)
                                            + (size_t)(rowi * 40 + s) * 8);
            a0 += __uint_as_float(u.x << 16);
            a1 += __uint_as_float(u.x & 0xFFFF0000u);
            a2 += __uint_as_float(u.y << 16);
            a3 += __uint_as_float(u.y & 0xFFFF0000u);
        }
        ((float4*)part)[g * 40 + s] = make_float4(a0, a1, a2, a3);
    }
    __syncthreads();

    if (t < BXH) {
        float sum = 0.0f;
        #pragma unroll
        for (int k = 0; k < 16; ++k) sum += part[k * BXH + t];
        row[t] = sum;
    }
    __syncthreads();

    if (t < WW) {
        float acc = 0.0f;
        #pragma unroll 4
        for (int k = 0; k < BXH; ++k)
            acc += row[k] * gxl[t * (BXH + 1) + k];
        ws[POFF + rowi * WW + t] = acc;
    }
}

// ---------------------------------------------------------------------------
// K3: 50 blocks, block h: img[h][w] = sum_r gy[h][r] * P[r][w].
// Last-done block (device atomic ticket) computes max + normalize + writes out.
// (No block ever waits on another — only the last one proceeds.)
// ---------------------------------------------------------------------------
__global__ __launch_bounds__(256) void pie_c2(float* __restrict__ ws,
                                              float* __restrict__ out)
{
    __shared__ float part[5 * WW];
    __shared__ float redmax[4];
    __shared__ int is_last;
    const int h = blockIdx.x;
    const int t = threadIdx.x;

    if (t < 5 * WW) {
        const int w = t % WW;
        const int c = t / WW;                // 0..4, 48 rows each
        const float* gy = ws + GYOFF + h * BYH;
        const float* P  = ws + POFF;
        const int r0 = c * (BYH / 5);
        float acc = 0.0f;
        #pragma unroll 4
        for (int r = r0; r < r0 + BYH / 5; ++r)
            acc += gy[r] * P[r * WW + w];
        part[t] = acc;
    }
    __syncthreads();
    if (t < WW)
        ws[IMGOFF + h * WW + t] = part[t] + part[WW + t] + part[2 * WW + t]
                                + part[3 * WW + t] + part[4 * WW + t];
    __threadfence();                         // release img row before ticket
    __syncthreads();
    if (t == 0) {
        const int old = atomicAdd((int*)ws + CNTOFF, 1);
        is_last = (old == HH - 1);
    }
    __syncthreads();
    if (!is_last) return;
    __threadfence();                         // acquire all img rows

    float m = -1e30f;
    for (int i = t; i < HH * WW; i += 256) m = fmaxf(m, ws[IMGOFF + i]);
    #pragma unroll
    for (int off = 32; off > 0; off >>= 1)
        m = fmaxf(m, __shfl_down(m, off));
    const int wv = t >> 6, ln = t & 63;
    if (ln == 0) redmax[wv] = m;
    __syncthreads();
    if (t == 0)
        redmax[0] = fmaxf(fmaxf(redmax[0], redmax[1]), fmaxf(redmax[2], redmax[3]));
    __syncthreads();

    const float inv = 1.0f / (redmax[0] + EPSF);
    for (int i = t; i < HH * WW; i += 256) out[i] = ws[IMGOFF + i] * inv;
}

// ---------------------------------------------------------------------------
extern "C" void kernel_launch(void* const* d_in, const int* in_sizes, int n_in,
                              void* d_out, int out_size, void* d_ws, size_t ws_size,
                              hipStream_t stream) {
    const float4* pairs4 = (const float4*)d_in[0];
    const float*  sigma  = (const float*)d_in[1];
    const float*  grid_x = (const float*)d_in[2];
    const float*  grid_y = (const float*)d_in[3];
    float* ws  = (float*)d_ws;
    float* out = (float*)d_out;
    const int n = in_sizes[0] / 2;

    // replica count from available workspace (bf16 replicas: 76.8 KB each)
    const long avail_bytes = (long)ws_size - (long)REPOFF * 4;
    long cap = avail_bytes / (REPSZ * 2);
    int R = (int)(cap < 256 ? cap : 256);
    if (R < 1) R = 1;

    pie_hist_lds<<<R, 1024, 0, stream>>>(pairs4, n, grid_x, grid_y, sigma, ws, R);
    pie_c1<<<BYH, 640, 0, stream>>>(ws, R);
    pie_c2<<<HH, 256, 0, stream>>>(ws, out);
}